// Round 10
// baseline (231.564 us; speedup 1.0000x reference)
//
#include <hip/hip_runtime.h>
#include <hip/hip_bf16.h>

#define NB 2
#define CCH 256
#define NPIX 9216      // 96*96
#define KCH 32
#define NTILE 288      // NPIX / 32
// sqrt( (1/sqrt(32)) * log2(e) ): folded into q at projection time, so
// S = (qP . kP) comes out directly in log2 units (softmax via exp2).
#define SQSCALE 0.5050098f

// workspace strides (per batch)
#define QPA_B 73728u     // 288 tiles * 2 hi * 32 lanes * 4 dwords
#define VBS_B 294912u    // 288 tiles * 2 half * 32 rows * 2 hi * 8 u16

typedef __attribute__((ext_vector_type(8)))  short short8;   // bf16x8 MFMA operand
typedef __attribute__((ext_vector_type(16))) float f32x16;   // 32x32 accumulator
typedef __attribute__((ext_vector_type(4)))  unsigned uint4v;

union ABu { unsigned u[4]; uint4v v4; short8 s; };

__device__ __forceinline__ unsigned pk2(float a, float b) {
  __hip_bfloat162 h = __float22bfloat162_rn(make_float2(a, b));
  unsigned r; __builtin_memcpy(&r, &h, 4); return r;
}
__device__ __forceinline__ unsigned short bf1(float a) {
  __hip_bfloat16 h = __float2bfloat16(a);
  unsigned short r; __builtin_memcpy(&r, &h, 2); return r;
}
__device__ __forceinline__ float bfx(unsigned short h) {   // bf16 -> f32 (exact)
  unsigned v = ((unsigned)h) << 16;
  float f; __builtin_memcpy(&f, &v, 4); return f;
}
// split a,b into bf16 hi pair and bf16 lo (residual) pair, packed dwords
__device__ __forceinline__ void split_pk(float a, float b, unsigned &hp, unsigned &lp) {
  unsigned short ha = bf1(a), hb_ = bf1(b);
  hp = (unsigned)ha | ((unsigned)hb_ << 16);
  unsigned short la = bf1(a - bfx(ha)), lb = bf1(b - bfx(hb_));
  lp = (unsigned)la | ((unsigned)lb << 16);
}
// exchange halves: after swap both lane-halves hold both operand words
__device__ __forceinline__ void plswap(unsigned &a, unsigned &b) {
  auto r = __builtin_amdgcn_permlane32_swap(a, b, false, false);
  a = r[0]; b = r[1];
}

#define MFMA32(a, b, c) __builtin_amdgcn_mfma_f32_32x32x16_bf16((a), (b), (c), 0, 0, 0)

// ---------------- MFMA projection: q = (Wq*human + bq)*scale, v = Wd*x + bd ----
// 576 blocks x 8 waves (8-way K-split over 256 channels, 32 each) for 4608
// waves of latency hiding. Split-bf16 (hi+lo, 3-term) keeps ~f32 precision.
__global__ __launch_bounds__(512, 4) void proj_mfma(
    const float* __restrict__ x, const float* __restrict__ human,
    const float* __restrict__ Wq, const float* __restrict__ bq,
    const float* __restrict__ Wd, const float* __restrict__ bd,
    unsigned* __restrict__ qPA,         // (B, 288, 2, 32, 4) kc-pairs 0..7
    unsigned* __restrict__ qPB,         // (B, 288, 2, 32, 4) kc-pairs 8..15
    unsigned short* __restrict__ vBS)   // (B, 288, 2, 32, 2, 8) bf16
{
  __shared__ float4 slab[8][8][64];   // 64 KB: [wave][frag-quad][lane]
  const int tid = threadIdx.x;
  const int w   = tid >> 6;           // K-eighth
  const int l   = tid & 63;
  const int hi  = l >> 5;
  const int ql  = l & 31;
  const int blk = blockIdx.x;         // 576
  const int b   = blk / NTILE;
  const int tN  = blk % NTILE;
  const int n0  = tN * 32;
  const int c0  = w * 32;
  const float* hb = human + (size_t)b*CCH*NPIX;
  const float* xb = x + (size_t)b*CCH*NPIX;

  ABu aqh[2], aqlo[2], adh[2], adlo[2];
#pragma unroll
  for (int s = 0; s < 2; ++s) {
    const int cbase = c0 + 16*s + 8*hi;
#pragma unroll
    for (int j = 0; j < 4; ++j) {
      const float q0 = Wq[ql*CCH + cbase + 2*j], q1 = Wq[ql*CCH + cbase + 2*j + 1];
      const float d0 = Wd[ql*CCH + cbase + 2*j], d1 = Wd[ql*CCH + cbase + 2*j + 1];
      split_pk(q0, q1, aqh[s].u[j], aqlo[s].u[j]);
      split_pk(d0, d1, adh[s].u[j], adlo[s].u[j]);
    }
  }

  f32x16 qa, va;
#pragma unroll
  for (int r = 0; r < 16; ++r) { qa[r] = 0.f; va[r] = 0.f; }

#pragma unroll
  for (int s = 0; s < 2; ++s) {
    const int cbase = c0 + 16*s + 8*hi;
    ABu bhh, bhl, bxh, bxl;
#pragma unroll
    for (int j = 0; j < 4; ++j) {
      const float h0 = hb[(size_t)(cbase + 2*j  )*NPIX + n0 + ql];
      const float h1 = hb[(size_t)(cbase + 2*j+1)*NPIX + n0 + ql];
      const float x0 = xb[(size_t)(cbase + 2*j  )*NPIX + n0 + ql];
      const float x1 = xb[(size_t)(cbase + 2*j+1)*NPIX + n0 + ql];
      split_pk(h0, h1, bhh.u[j], bhl.u[j]);
      split_pk(x0, x1, bxh.u[j], bxl.u[j]);
    }
    qa = MFMA32(aqh[s].s,  bhh.s, qa);
    qa = MFMA32(aqh[s].s,  bhl.s, qa);
    qa = MFMA32(aqlo[s].s, bhh.s, qa);
    va = MFMA32(adh[s].s,  bxh.s, va);
    va = MFMA32(adh[s].s,  bxl.s, va);
    va = MFMA32(adlo[s].s, bxh.s, va);
  }

#pragma unroll
  for (int jf = 0; jf < 4; ++jf) {
    slab[w][jf  ][l] = make_float4(qa[4*jf], qa[4*jf+1], qa[4*jf+2], qa[4*jf+3]);
    slab[w][4+jf][l] = make_float4(va[4*jf], va[4*jf+1], va[4*jf+2], va[4*jf+3]);
  }
  __syncthreads();
  if (w == 0) {
    unsigned* qpa = qPA + (size_t)b*QPA_B;
    unsigned* qpb = qPB + (size_t)b*QPA_B;
    unsigned short* vbs = vBS + (size_t)b*VBS_B;
#pragma unroll
    for (int jf = 0; jf < 4; ++jf) {
      const int kc = 8*jf + 4*hi;
      float sx=0, sy=0, sz=0, sw=0, tx=0, ty=0, tz=0, tw=0;
#pragma unroll
      for (int ww = 0; ww < 8; ++ww) {
        const float4 sq = slab[ww][jf][l];
        const float4 tv = slab[ww][4+jf][l];
        sx += sq.x; sy += sq.y; sz += sq.z; sw += sq.w;
        tx += tv.x; ty += tv.y; tz += tv.z; tw += tv.w;
      }
      const float v0 = (sx + bq[kc+0]) * SQSCALE;
      const float v1 = (sy + bq[kc+1]) * SQSCALE;
      const float v2 = (sz + bq[kc+2]) * SQSCALE;
      const float v3 = (sw + bq[kc+3]) * SQSCALE;
      const int p0 = 4*jf + 2*hi;
      unsigned* a0p = (p0 < 8) ? qpa : qpb;
      a0p[(size_t)tN*256 + ((p0&7)>>2)*128 + ql*4 + (p0&3)] = pk2(v0, v1);
      const int p1 = p0 + 1;
      unsigned* a1p = (p1 < 8) ? qpa : qpb;
      a1p[(size_t)tN*256 + ((p1&7)>>2)*128 + ql*4 + (p1&3)] = pk2(v2, v3);
      const size_t vbase = (size_t)tN*1024 + (size_t)(ql>>4)*512 + (size_t)(ql&15);
      vbs[vbase + (size_t)(kc+0)*16] = bf1(tx + bd[kc+0]);
      vbs[vbase + (size_t)(kc+1)*16] = bf1(ty + bd[kc+1]);
      vbs[vbase + (size_t)(kc+2)*16] = bf1(tz + bd[kc+2]);
      vbs[vbase + (size_t)(kc+3)*16] = bf1(tw + bd[kc+3]);
    }
  }
}

// ---------------- attention main: 1152 blocks x 4 independent waves ----------
// Wave = (64-query tile, key-16th). 4 waves/block share the same query tile
// (consecutive key-16ths) -> shared Q lines in L1/L2; no LDS, no barriers.
// 4.5 blocks/CU = 18 resident waves/CU (vs 8.6 with single-wave blocks).
__global__ __launch_bounds__(256, 5) void attn_wave(
    const unsigned* __restrict__ qPA, const unsigned* __restrict__ qPB,
    const unsigned short* __restrict__ vBS,
    float4* __restrict__ pO4,           // [4608][2][4][64] float4
    float* __restrict__ pL)             // [4608][64]
{
  const int tid = threadIdx.x;
  const int w   = tid >> 6;
  const int l   = tid & 63;
  const int hi  = l >> 5;
  const int ql  = l & 31;
  const int bswz = ((blockIdx.x & 7)*144 + (blockIdx.x >> 3));  // 1152 = 8*144
  const int swz  = bswz*4 + w;              // global wave 0..4607
  const int b   = swz / 2304;
  const int r2  = swz % 2304;
  const int qt  = r2 >> 4;                  // 0..143 (64-query tile)
  const int ks  = r2 & 15;                  // key-16th

  const unsigned* qa_ = qPA + (size_t)b*QPA_B;
  const unsigned* qb_ = qPB + (size_t)b*QPA_B;
  const unsigned short* vb_ = vBS + (size_t)b*VBS_B;

  ABu bqA1, bqA2, bqB1, bqB2;
  bqA1.v4 = *(const uint4v*)(qa_ + (size_t)(2*qt  )*256 + hi*128 + ql*4);
  bqA2.v4 = *(const uint4v*)(qb_ + (size_t)(2*qt  )*256 + hi*128 + ql*4);
  bqB1.v4 = *(const uint4v*)(qa_ + (size_t)(2*qt+1)*256 + hi*128 + ql*4);
  bqB2.v4 = *(const uint4v*)(qb_ + (size_t)(2*qt+1)*256 + hi*128 + ql*4);

  f32x16 OA, OB, Z;
#pragma unroll
  for (int r = 0; r < 16; ++r) { OA[r] = 0.f; OB[r] = 0.f; Z[r] = 0.f; }
  float lsA = 0.f, lsB = 0.f;

  for (int it = 0; it < 18; ++it) {
    const int t = ks*18 + it;
    const size_t ko = (size_t)t*256 + hi*128 + ql*4;
    ABu ak1, ak2;
    ak1.v4 = *(const uint4v*)(qa_ + ko);
    ak2.v4 = *(const uint4v*)(qb_ + ko);
    const size_t vo = (size_t)t*1024 + (size_t)ql*16 + hi*8;
    const short8 av1 = *(const short8*)(vb_ + vo);
    const short8 av2 = *(const short8*)(vb_ + vo + 512);

    // ---- frag A ----
    f32x16 s = MFMA32(ak1.s, bqA1.s, Z);
    s = MFMA32(ak2.s, bqA2.s, s);
    float p[16];
#pragma unroll
    for (int r = 0; r < 16; ++r) p[r] = __builtin_amdgcn_exp2f(s[r]);
    lsA += (((p[0]+p[1])+(p[2]+p[3])) + ((p[4]+p[5])+(p[6]+p[7])))
         + (((p[8]+p[9])+(p[10]+p[11])) + ((p[12]+p[13])+(p[14]+p[15])));
    {
      unsigned a0 = pk2(p[0],p[1]),  a1 = pk2(p[2],p[3]);
      unsigned b0 = pk2(p[4],p[5]),  b1 = pk2(p[6],p[7]);
      unsigned a2 = pk2(p[8],p[9]),  a3 = pk2(p[10],p[11]);
      unsigned b2 = pk2(p[12],p[13]),b3 = pk2(p[14],p[15]);
      plswap(a0,b0); plswap(a1,b1); plswap(a2,b2); plswap(a3,b3);
      ABu pb1, pb2;
      pb1.u[0]=a0; pb1.u[1]=a1; pb1.u[2]=b0; pb1.u[3]=b1;
      pb2.u[0]=a2; pb2.u[1]=a3; pb2.u[2]=b2; pb2.u[3]=b3;
      OA = MFMA32(av1, pb1.s, OA);
      OA = MFMA32(av2, pb2.s, OA);
    }
    // ---- frag B ----
    s = MFMA32(ak1.s, bqB1.s, Z);
    s = MFMA32(ak2.s, bqB2.s, s);
#pragma unroll
    for (int r = 0; r < 16; ++r) p[r] = __builtin_amdgcn_exp2f(s[r]);
    lsB += (((p[0]+p[1])+(p[2]+p[3])) + ((p[4]+p[5])+(p[6]+p[7])))
         + (((p[8]+p[9])+(p[10]+p[11])) + ((p[12]+p[13])+(p[14]+p[15])));
    {
      unsigned a0 = pk2(p[0],p[1]),  a1 = pk2(p[2],p[3]);
      unsigned b0 = pk2(p[4],p[5]),  b1 = pk2(p[6],p[7]);
      unsigned a2 = pk2(p[8],p[9]),  a3 = pk2(p[10],p[11]);
      unsigned b2 = pk2(p[12],p[13]),b3 = pk2(p[14],p[15]);
      plswap(a0,b0); plswap(a1,b1); plswap(a2,b2); plswap(a3,b3);
      ABu pb1, pb2;
      pb1.u[0]=a0; pb1.u[1]=a1; pb1.u[2]=b0; pb1.u[3]=b1;
      pb2.u[0]=a2; pb2.u[1]=a3; pb2.u[2]=b2; pb2.u[3]=b3;
      OB = MFMA32(av1, pb1.s, OB);
      OB = MFMA32(av2, pb2.s, OB);
    }
  }

  lsA += __shfl_xor(lsA, 32);
  lsB += __shfl_xor(lsB, 32);
#pragma unroll
  for (int rq = 0; rq < 4; ++rq) {
    pO4[((size_t)swz*8 + rq    )*64 + l] = make_float4(OA[4*rq], OA[4*rq+1], OA[4*rq+2], OA[4*rq+3]);
    pO4[((size_t)swz*8 + 4 + rq)*64 + l] = make_float4(OB[4*rq], OB[4*rq+1], OB[4*rq+2], OB[4*rq+3]);
  }
  if (l < 32) {
    pL[(size_t)swz*64 + l]      = lsA;
    pL[(size_t)swz*64 + 32 + l] = lsB;
  }
}

// ---------------- attention merge: sum 16 key-splits, normalize --------------
// writes ctx PIXEL-MAJOR: ctxP[b][n][kc], 32 f32 per pixel
__global__ __launch_bounds__(64) void attn_merge(
    const float4* __restrict__ pO4, const float* __restrict__ pL,
    float* __restrict__ ctxP)
{
  const int l   = threadIdx.x;           // q64
  const int blk = blockIdx.x;            // 1152 = 2 * 144 * 4
  const int b   = blk / 576;
  const int rem = blk % 576;
  const int qt  = rem >> 2;
  const int kcq = rem & 3;
  const int f   = l >> 5;
  const int qlm = l & 31;

  float ax=0,ay=0,az=0,aw=0, bx=0,by=0,bz=0,bw=0, L=0;
  const size_t base = (size_t)b*2304 + (size_t)qt*16;
#pragma unroll 4
  for (int ks = 0; ks < 16; ++ks) {
    const size_t pb_ = base + ks;
    const float4* pp = pO4 + (pb_*8 + (size_t)f*4 + kcq)*64;
    const float4 t0 = pp[qlm];
    const float4 t1 = pp[qlm + 32];
    ax += t0.x; ay += t0.y; az += t0.z; aw += t0.w;
    bx += t1.x; by += t1.y; bz += t1.z; bw += t1.w;
    L  += pL[pb_*64 + l];
  }
  const float inv = 1.f / L;
  float* cp = ctxP + ((size_t)b*NPIX + (size_t)qt*64 + l)*32 + kcq*8;
  ((float4*)cp)[0] = make_float4(ax*inv, ay*inv, az*inv, aw*inv);
  ((float4*)cp)[1] = make_float4(bx*inv, by*inv, bz*inv, bw*inv);
}

// ---------------- fallback attention (LDS merge), pixel-major ctx ------------
__global__ __launch_bounds__(512, 6) void attn_mfma(
    const unsigned* __restrict__ qPA, const unsigned* __restrict__ qPB,
    const unsigned short* __restrict__ vBS,
    float* __restrict__ ctxP)
{
  __shared__ float slab[8][32][32];
  __shared__ float mlbuf[8][32];
  const int tid = threadIdx.x;
  const int w   = tid >> 6;
  const int l   = tid & 63;
  const int hi  = l >> 5;
  const int ql  = l & 31;
  const int blk = blockIdx.x;
  const int b   = blk / NTILE;
  const int tq  = blk % NTILE;
  const int q0  = tq * 32;

  const unsigned* qa_ = qPA + (size_t)b*QPA_B;
  const unsigned* qb_ = qPB + (size_t)b*QPA_B;
  const unsigned short* vb_ = vBS + (size_t)b*VBS_B;

  ABu bq1, bq2;
  bq1.v4 = *(const uint4v*)(qa_ + (size_t)tq*256 + hi*128 + ql*4);
  bq2.v4 = *(const uint4v*)(qb_ + (size_t)tq*256 + hi*128 + ql*4);

  f32x16 O;
#pragma unroll
  for (int r = 0; r < 16; ++r) O[r] = 0.f;
  float lsum = 0.f;

  for (int it = 0; it < 36; ++it) {
    const int t = it*8 + w;
    const size_t ko = (size_t)t*256 + hi*128 + ql*4;
    ABu ak1, ak2;
    ak1.v4 = *(const uint4v*)(qa_ + ko);
    ak2.v4 = *(const uint4v*)(qb_ + ko);
    const size_t vo = (size_t)t*1024 + (size_t)ql*16 + hi*8;
    const short8 av1 = *(const short8*)(vb_ + vo);
    const short8 av2 = *(const short8*)(vb_ + vo + 512);

    f32x16 s;
#pragma unroll
    for (int r = 0; r < 16; ++r) s[r] = 0.f;
    s = MFMA32(ak1.s, bq1.s, s);
    s = MFMA32(ak2.s, bq2.s, s);

    float p[16];
#pragma unroll
    for (int r = 0; r < 16; ++r) p[r] = __builtin_amdgcn_exp2f(s[r]);
    lsum += (((p[0]+p[1])+(p[2]+p[3])) + ((p[4]+p[5])+(p[6]+p[7])))
          + (((p[8]+p[9])+(p[10]+p[11])) + ((p[12]+p[13])+(p[14]+p[15])));

    unsigned a0 = pk2(p[0],p[1]),  a1 = pk2(p[2],p[3]);
    unsigned b0 = pk2(p[4],p[5]),  b1 = pk2(p[6],p[7]);
    unsigned a2 = pk2(p[8],p[9]),  a3 = pk2(p[10],p[11]);
    unsigned b2 = pk2(p[12],p[13]),b3 = pk2(p[14],p[15]);
    plswap(a0,b0); plswap(a1,b1); plswap(a2,b2); plswap(a3,b3);
    ABu pb1, pb2;
    pb1.u[0]=a0; pb1.u[1]=a1; pb1.u[2]=b0; pb1.u[3]=b1;
    pb2.u[0]=a2; pb2.u[1]=a3; pb2.u[2]=b2; pb2.u[3]=b3;

    O = MFMA32(av1, pb1.s, O);
    O = MFMA32(av2, pb2.s, O);
  }

  lsum += __shfl_xor(lsum, 32);
  if (hi == 0) mlbuf[w][ql] = lsum;
#pragma unroll
  for (int r = 0; r < 16; ++r)
    slab[w][(r&3) + 8*(r>>2) + 4*hi][ql] = O[r];
  __syncthreads();

  {
    const int q  = tid & 31;
    const int kh = tid >> 5;
    float L = 0.f;
#pragma unroll
    for (int ww = 0; ww < 8; ++ww) L += mlbuf[ww][q];
    const float inv = 1.f / L;
#pragma unroll
    for (int i = 0; i < 2; ++i) {
      const int kc = kh + 16*i;
      float acc = 0.f;
#pragma unroll
      for (int ww = 0; ww < 8; ++ww) acc += slab[ww][kc][q];
      ctxP[((size_t)b*NPIX + q0 + q)*32 + kc] = acc * inv;
    }
  }
}

// ---------------- g = relu(Wf*ctx + bf), pixel-major ------------------------
// 288 blocks x 256 thr; thread = (pixel, channel-quarter of 8).
__global__ __launch_bounds__(256) void g_kernel(
    const float* __restrict__ ctxP, const float* __restrict__ Wf,
    const float* __restrict__ bf, float* __restrict__ gP)
{
  __shared__ float4 swf[256];   // Wf 32x32
  const int tid = threadIdx.x;
  const int blk = blockIdx.x;        // 288 = 2*144
  const int b   = blk / 144;
  const int pg  = blk % 144;
  swf[tid] = ((const float4*)Wf)[tid];
  __syncthreads();
  const int nl = tid >> 2;           // 0..63
  const int cq = tid & 3;
  const int n  = pg*64 + nl;
  float cc[32];
  const float4* cp = (const float4*)(ctxP + ((size_t)b*NPIX + n)*32);
#pragma unroll
  for (int i = 0; i < 8; ++i) {
    const float4 t = cp[i];
    cc[4*i] = t.x; cc[4*i+1] = t.y; cc[4*i+2] = t.z; cc[4*i+3] = t.w;
  }
  float r[8];
#pragma unroll
  for (int jj = 0; jj < 8; ++jj) {
    const int j = cq*8 + jj;
    float acc = bf[j];
#pragma unroll
    for (int k8 = 0; k8 < 8; ++k8) {
      const float4 wv = swf[j*8 + k8];
      acc += wv.x*cc[4*k8] + wv.y*cc[4*k8+1] + wv.z*cc[4*k8+2] + wv.w*cc[4*k8+3];
    }
    r[jj] = fmaxf(acc, 0.f);
  }
  float4* go = (float4*)(gP + ((size_t)b*NPIX + n)*32 + cq*8);
  go[0] = make_float4(r[0], r[1], r[2], r[3]);
  go[1] = make_float4(r[4], r[5], r[6], r[7]);
}

// ---------------- epilogue: out = x + Wu*g + bu ------------------------------
// 1152 blocks x 256 thr (4608 waves). Thread = (pixel, 16-channel group).
__global__ __launch_bounds__(256) void epi_v3(
    const float* __restrict__ x, const float* __restrict__ gP,
    const float* __restrict__ Wu, const float* __restrict__ bu,
    float* __restrict__ out)
{
  __shared__ float4 swu[512];   // 64 Wu rows x 32 f32 = 8 KB
  const int tid = threadIdx.x;
  const int w   = tid >> 6;
  const int l   = tid & 63;
  const int blk = blockIdx.x;          // 1152 = 2 * 4 * 144
  const int b   = blk / 576;
  const int rem = blk % 576;
  const int cquad = rem / 144;         // 0..3
  const int pg  = rem % 144;
  const int co  = cquad*4 + w;         // 16-channel group 0..15
  const int n   = pg*64 + l;
#pragma unroll
  for (int it = 0; it < 2; ++it)
    swu[it*256 + tid] = ((const float4*)Wu)[cquad*512 + it*256 + tid];
  __syncthreads();
  float gg[32];
  const float4* gp = (const float4*)(gP + ((size_t)b*NPIX + n)*32);
#pragma unroll
  for (int i = 0; i < 8; ++i) {
    const float4 t = gp[i];
    gg[4*i] = t.x; gg[4*i+1] = t.y; gg[4*i+2] = t.z; gg[4*i+3] = t.w;
  }
  const float* xb = x + ((size_t)b*CCH + co*16)*NPIX + n;
  float* ob = out + ((size_t)b*CCH + co*16)*NPIX + n;
#pragma unroll
  for (int c = 0; c < 16; ++c) {
    float acc = bu[co*16 + c];
#pragma unroll
    for (int j = 0; j < 8; ++j) {
      const float4 wv = swu[(w*16 + c)*8 + j];
      acc += wv.x*gg[4*j] + wv.y*gg[4*j+1] + wv.z*gg[4*j+2] + wv.w*gg[4*j+3];
    }
    ob[(size_t)c*NPIX] = xb[(size_t)c*NPIX] + acc;
  }
}

extern "C" void kernel_launch(void* const* d_in, const int* in_sizes, int n_in,
                              void* d_out, int out_size, void* d_ws, size_t ws_size,
                              hipStream_t stream) {
  (void)in_sizes; (void)n_in; (void)out_size;
  const float* x     = (const float*)d_in[0];
  const float* human = (const float*)d_in[1];
  const float* Wq    = (const float*)d_in[2];
  const float* bq    = (const float*)d_in[3];
  const float* Wd    = (const float*)d_in[4];
  const float* bd    = (const float*)d_in[5];
  const float* Wf    = (const float*)d_in[6];
  const float* bf    = (const float*)d_in[7];
  const float* Wu    = (const float*)d_in[8];
  const float* bu    = (const float*)d_in[9];
  float* out = (float*)d_out;

  unsigned* qPA       = (unsigned*)d_ws;
  unsigned* qPB       = qPA + (size_t)NB*QPA_B;
  unsigned short* vBS = (unsigned short*)(qPB + (size_t)NB*QPA_B);
  float* ctxP         = (float*)(vBS + (size_t)NB*VBS_B);          // NB*NPIX*32 f32
  float* gP           = ctxP + (size_t)NB*NPIX*32;                 // NB*NPIX*32 f32
  float4* pO4         = (float4*)(gP + (size_t)NB*NPIX*32);        // 4608*8*64 float4
  float* pL           = (float*)(pO4 + (size_t)4608*8*64);         // 4608*64 f32

  const size_t need = ((char*)(pL + (size_t)4608*64)) - (char*)d_ws;

  proj_mfma<<<576, 512, 0, stream>>>(x, human, Wq, bq, Wd, bd, qPA, qPB, vBS);
  if (ws_size >= need) {
    attn_wave<<<1152, 256, 0, stream>>>(qPA, qPB, vBS, pO4, pL);
    attn_merge<<<1152, 64, 0, stream>>>(pO4, pL, ctxP);
  } else {
    attn_mfma<<<576, 512, 0, stream>>>(qPA, qPB, vBS, ctxP);
  }
  g_kernel<<<288, 256, 0, stream>>>(ctxP, Wf, bf, gP);
  epi_v3<<<1152, 256, 0, stream>>>(x, gP, Wu, bu, out);
}

// Round 11
// 197.361 us; speedup vs baseline: 1.1733x; 1.1733x over previous
//
#include <hip/hip_runtime.h>
#include <hip/hip_bf16.h>

#define NB 2
#define CCH 256
#define NPIX 9216      // 96*96
#define KCH 32
#define NTILE 288      // NPIX / 32
// sqrt( (1/sqrt(32)) * log2(e) ): folded into q at projection time, so
// S = (qP . kP) comes out directly in log2 units (softmax via exp2).
#define SQSCALE 0.5050098f

// workspace strides (per batch)
#define QPA_B 73728u     // 288 tiles * 2 hi * 32 lanes * 4 dwords
#define VBS_B 294912u    // 288 tiles * 2 half * 32 rows * 2 hi * 8 u16

typedef __attribute__((ext_vector_type(8)))  short short8;   // bf16x8 MFMA operand
typedef __attribute__((ext_vector_type(16))) float f32x16;   // 32x32 accumulator
typedef __attribute__((ext_vector_type(4)))  unsigned uint4v;

union ABu { unsigned u[4]; uint4v v4; short8 s; };

__device__ __forceinline__ unsigned pk2(float a, float b) {
  __hip_bfloat162 h = __float22bfloat162_rn(make_float2(a, b));
  unsigned r; __builtin_memcpy(&r, &h, 4); return r;
}
__device__ __forceinline__ unsigned short bf1(float a) {
  __hip_bfloat16 h = __float2bfloat16(a);
  unsigned short r; __builtin_memcpy(&r, &h, 2); return r;
}
__device__ __forceinline__ float bfx(unsigned short h) {   // bf16 -> f32 (exact)
  unsigned v = ((unsigned)h) << 16;
  float f; __builtin_memcpy(&f, &v, 4); return f;
}
// split a,b into bf16 hi pair and bf16 lo (residual) pair, packed dwords
__device__ __forceinline__ void split_pk(float a, float b, unsigned &hp, unsigned &lp) {
  unsigned short ha = bf1(a), hb_ = bf1(b);
  hp = (unsigned)ha | ((unsigned)hb_ << 16);
  unsigned short la = bf1(a - bfx(ha)), lb = bf1(b - bfx(hb_));
  lp = (unsigned)la | ((unsigned)lb << 16);
}
// exchange halves: after swap both lane-halves hold both operand words
__device__ __forceinline__ void plswap(unsigned &a, unsigned &b) {
  auto r = __builtin_amdgcn_permlane32_swap(a, b, false, false);
  a = r[0]; b = r[1];
}

#define MFMA32(a, b, c) __builtin_amdgcn_mfma_f32_32x32x16_bf16((a), (b), (c), 0, 0, 0)

// ---------------- MFMA projection: q = (Wq*human + bq)*scale, v = Wd*x + bd ----
// 576 blocks x 8 waves (8-way K-split over 256 channels, 32 each) for 4608
// waves of latency hiding. Split-bf16 (hi+lo, 3-term) keeps ~f32 precision.
__global__ __launch_bounds__(512, 4) void proj_mfma(
    const float* __restrict__ x, const float* __restrict__ human,
    const float* __restrict__ Wq, const float* __restrict__ bq,
    const float* __restrict__ Wd, const float* __restrict__ bd,
    unsigned* __restrict__ qPA,         // (B, 288, 2, 32, 4) kc-pairs 0..7
    unsigned* __restrict__ qPB,         // (B, 288, 2, 32, 4) kc-pairs 8..15
    unsigned short* __restrict__ vBS)   // (B, 288, 2, 32, 2, 8) bf16
{
  __shared__ float4 slab[8][8][64];   // 64 KB: [wave][frag-quad][lane]
  const int tid = threadIdx.x;
  const int w   = tid >> 6;           // K-eighth
  const int l   = tid & 63;
  const int hi  = l >> 5;
  const int ql  = l & 31;
  const int blk = blockIdx.x;         // 576
  const int b   = blk / NTILE;
  const int tN  = blk % NTILE;
  const int n0  = tN * 32;
  const int c0  = w * 32;
  const float* hb = human + (size_t)b*CCH*NPIX;
  const float* xb = x + (size_t)b*CCH*NPIX;

  ABu aqh[2], aqlo[2], adh[2], adlo[2];
#pragma unroll
  for (int s = 0; s < 2; ++s) {
    const int cbase = c0 + 16*s + 8*hi;
#pragma unroll
    for (int j = 0; j < 4; ++j) {
      const float q0 = Wq[ql*CCH + cbase + 2*j], q1 = Wq[ql*CCH + cbase + 2*j + 1];
      const float d0 = Wd[ql*CCH + cbase + 2*j], d1 = Wd[ql*CCH + cbase + 2*j + 1];
      split_pk(q0, q1, aqh[s].u[j], aqlo[s].u[j]);
      split_pk(d0, d1, adh[s].u[j], adlo[s].u[j]);
    }
  }

  f32x16 qa, va;
#pragma unroll
  for (int r = 0; r < 16; ++r) { qa[r] = 0.f; va[r] = 0.f; }

#pragma unroll
  for (int s = 0; s < 2; ++s) {
    const int cbase = c0 + 16*s + 8*hi;
    ABu bhh, bhl, bxh, bxl;
#pragma unroll
    for (int j = 0; j < 4; ++j) {
      const float h0 = hb[(size_t)(cbase + 2*j  )*NPIX + n0 + ql];
      const float h1 = hb[(size_t)(cbase + 2*j+1)*NPIX + n0 + ql];
      const float x0 = xb[(size_t)(cbase + 2*j  )*NPIX + n0 + ql];
      const float x1 = xb[(size_t)(cbase + 2*j+1)*NPIX + n0 + ql];
      split_pk(h0, h1, bhh.u[j], bhl.u[j]);
      split_pk(x0, x1, bxh.u[j], bxl.u[j]);
    }
    qa = MFMA32(aqh[s].s,  bhh.s, qa);
    qa = MFMA32(aqh[s].s,  bhl.s, qa);
    qa = MFMA32(aqlo[s].s, bhh.s, qa);
    va = MFMA32(adh[s].s,  bxh.s, va);
    va = MFMA32(adh[s].s,  bxl.s, va);
    va = MFMA32(adlo[s].s, bxh.s, va);
  }

#pragma unroll
  for (int jf = 0; jf < 4; ++jf) {
    slab[w][jf  ][l] = make_float4(qa[4*jf], qa[4*jf+1], qa[4*jf+2], qa[4*jf+3]);
    slab[w][4+jf][l] = make_float4(va[4*jf], va[4*jf+1], va[4*jf+2], va[4*jf+3]);
  }
  __syncthreads();
  if (w == 0) {
    unsigned* qpa = qPA + (size_t)b*QPA_B;
    unsigned* qpb = qPB + (size_t)b*QPA_B;
    unsigned short* vbs = vBS + (size_t)b*VBS_B;
#pragma unroll
    for (int jf = 0; jf < 4; ++jf) {
      const int kc = 8*jf + 4*hi;
      float sx=0, sy=0, sz=0, sw=0, tx=0, ty=0, tz=0, tw=0;
#pragma unroll
      for (int ww = 0; ww < 8; ++ww) {
        const float4 sq = slab[ww][jf][l];
        const float4 tv = slab[ww][4+jf][l];
        sx += sq.x; sy += sq.y; sz += sq.z; sw += sq.w;
        tx += tv.x; ty += tv.y; tz += tv.z; tw += tv.w;
      }
      const float v0 = (sx + bq[kc+0]) * SQSCALE;
      const float v1 = (sy + bq[kc+1]) * SQSCALE;
      const float v2 = (sz + bq[kc+2]) * SQSCALE;
      const float v3 = (sw + bq[kc+3]) * SQSCALE;
      const int p0 = 4*jf + 2*hi;
      unsigned* a0p = (p0 < 8) ? qpa : qpb;
      a0p[(size_t)tN*256 + ((p0&7)>>2)*128 + ql*4 + (p0&3)] = pk2(v0, v1);
      const int p1 = p0 + 1;
      unsigned* a1p = (p1 < 8) ? qpa : qpb;
      a1p[(size_t)tN*256 + ((p1&7)>>2)*128 + ql*4 + (p1&3)] = pk2(v2, v3);
      const size_t vbase = (size_t)tN*1024 + (size_t)(ql>>4)*512 + (size_t)(ql&15);
      vbs[vbase + (size_t)(kc+0)*16] = bf1(tx + bd[kc+0]);
      vbs[vbase + (size_t)(kc+1)*16] = bf1(ty + bd[kc+1]);
      vbs[vbase + (size_t)(kc+2)*16] = bf1(tz + bd[kc+2]);
      vbs[vbase + (size_t)(kc+3)*16] = bf1(tw + bd[kc+3]);
    }
  }
}

// ---------------- attention main: 1152 blocks x 4 independent waves ----------
// Wave = (64-query tile, key-16th). 4 waves/block share the same query tile
// (consecutive key-16ths) -> shared Q lines in L1/L2; no LDS, no barriers.
// launch_bounds (256,4): VGPR cap 128 -- (256,5) squeezed the allocator to 48
// VGPRs and spilled the accumulators (round-10 regression, 246 MB HBM traffic).
__global__ __launch_bounds__(256, 4) void attn_wave(
    const unsigned* __restrict__ qPA, const unsigned* __restrict__ qPB,
    const unsigned short* __restrict__ vBS,
    float4* __restrict__ pO4,           // [4608][2][4][64] float4
    float* __restrict__ pL)             // [4608][64]
{
  const int tid = threadIdx.x;
  const int w   = tid >> 6;
  const int l   = tid & 63;
  const int hi  = l >> 5;
  const int ql  = l & 31;
  const int bswz = ((blockIdx.x & 7)*144 + (blockIdx.x >> 3));  // 1152 = 8*144
  const int swz  = bswz*4 + w;              // global wave 0..4607
  const int b   = swz / 2304;
  const int r2  = swz % 2304;
  const int qt  = r2 >> 4;                  // 0..143 (64-query tile)
  const int ks  = r2 & 15;                  // key-16th

  const unsigned* qa_ = qPA + (size_t)b*QPA_B;
  const unsigned* qb_ = qPB + (size_t)b*QPA_B;
  const unsigned short* vb_ = vBS + (size_t)b*VBS_B;

  ABu bqA1, bqA2, bqB1, bqB2;
  bqA1.v4 = *(const uint4v*)(qa_ + (size_t)(2*qt  )*256 + hi*128 + ql*4);
  bqA2.v4 = *(const uint4v*)(qb_ + (size_t)(2*qt  )*256 + hi*128 + ql*4);
  bqB1.v4 = *(const uint4v*)(qa_ + (size_t)(2*qt+1)*256 + hi*128 + ql*4);
  bqB2.v4 = *(const uint4v*)(qb_ + (size_t)(2*qt+1)*256 + hi*128 + ql*4);

  f32x16 OA, OB, Z;
#pragma unroll
  for (int r = 0; r < 16; ++r) { OA[r] = 0.f; OB[r] = 0.f; Z[r] = 0.f; }
  float lsA = 0.f, lsB = 0.f;

  for (int it = 0; it < 18; ++it) {
    const int t = ks*18 + it;
    const size_t ko = (size_t)t*256 + hi*128 + ql*4;
    ABu ak1, ak2;
    ak1.v4 = *(const uint4v*)(qa_ + ko);
    ak2.v4 = *(const uint4v*)(qb_ + ko);
    const size_t vo = (size_t)t*1024 + (size_t)ql*16 + hi*8;
    const short8 av1 = *(const short8*)(vb_ + vo);
    const short8 av2 = *(const short8*)(vb_ + vo + 512);

    // ---- frag A ----
    f32x16 s = MFMA32(ak1.s, bqA1.s, Z);
    s = MFMA32(ak2.s, bqA2.s, s);
    float p[16];
#pragma unroll
    for (int r = 0; r < 16; ++r) p[r] = __builtin_amdgcn_exp2f(s[r]);
    lsA += (((p[0]+p[1])+(p[2]+p[3])) + ((p[4]+p[5])+(p[6]+p[7])))
         + (((p[8]+p[9])+(p[10]+p[11])) + ((p[12]+p[13])+(p[14]+p[15])));
    {
      unsigned a0 = pk2(p[0],p[1]),  a1 = pk2(p[2],p[3]);
      unsigned b0 = pk2(p[4],p[5]),  b1 = pk2(p[6],p[7]);
      unsigned a2 = pk2(p[8],p[9]),  a3 = pk2(p[10],p[11]);
      unsigned b2 = pk2(p[12],p[13]),b3 = pk2(p[14],p[15]);
      plswap(a0,b0); plswap(a1,b1); plswap(a2,b2); plswap(a3,b3);
      ABu pb1, pb2;
      pb1.u[0]=a0; pb1.u[1]=a1; pb1.u[2]=b0; pb1.u[3]=b1;
      pb2.u[0]=a2; pb2.u[1]=a3; pb2.u[2]=b2; pb2.u[3]=b3;
      OA = MFMA32(av1, pb1.s, OA);
      OA = MFMA32(av2, pb2.s, OA);
    }
    // ---- frag B ----
    s = MFMA32(ak1.s, bqB1.s, Z);
    s = MFMA32(ak2.s, bqB2.s, s);
#pragma unroll
    for (int r = 0; r < 16; ++r) p[r] = __builtin_amdgcn_exp2f(s[r]);
    lsB += (((p[0]+p[1])+(p[2]+p[3])) + ((p[4]+p[5])+(p[6]+p[7])))
         + (((p[8]+p[9])+(p[10]+p[11])) + ((p[12]+p[13])+(p[14]+p[15])));
    {
      unsigned a0 = pk2(p[0],p[1]),  a1 = pk2(p[2],p[3]);
      unsigned b0 = pk2(p[4],p[5]),  b1 = pk2(p[6],p[7]);
      unsigned a2 = pk2(p[8],p[9]),  a3 = pk2(p[10],p[11]);
      unsigned b2 = pk2(p[12],p[13]),b3 = pk2(p[14],p[15]);
      plswap(a0,b0); plswap(a1,b1); plswap(a2,b2); plswap(a3,b3);
      ABu pb1, pb2;
      pb1.u[0]=a0; pb1.u[1]=a1; pb1.u[2]=b0; pb1.u[3]=b1;
      pb2.u[0]=a2; pb2.u[1]=a3; pb2.u[2]=b2; pb2.u[3]=b3;
      OB = MFMA32(av1, pb1.s, OB);
      OB = MFMA32(av2, pb2.s, OB);
    }
  }

  lsA += __shfl_xor(lsA, 32);
  lsB += __shfl_xor(lsB, 32);
#pragma unroll
  for (int rq = 0; rq < 4; ++rq) {
    pO4[((size_t)swz*8 + rq    )*64 + l] = make_float4(OA[4*rq], OA[4*rq+1], OA[4*rq+2], OA[4*rq+3]);
    pO4[((size_t)swz*8 + 4 + rq)*64 + l] = make_float4(OB[4*rq], OB[4*rq+1], OB[4*rq+2], OB[4*rq+3]);
  }
  if (l < 32) {
    pL[(size_t)swz*64 + l]      = lsA;
    pL[(size_t)swz*64 + 32 + l] = lsB;
  }
}

// ---------------- attention merge: sum 16 key-splits, normalize --------------
// writes ctx PIXEL-MAJOR: ctxP[b][n][kc], 32 f32 per pixel
__global__ __launch_bounds__(64) void attn_merge(
    const float4* __restrict__ pO4, const float* __restrict__ pL,
    float* __restrict__ ctxP)
{
  const int l   = threadIdx.x;           // q64
  const int blk = blockIdx.x;            // 1152 = 2 * 144 * 4
  const int b   = blk / 576;
  const int rem = blk % 576;
  const int qt  = rem >> 2;
  const int kcq = rem & 3;
  const int f   = l >> 5;
  const int qlm = l & 31;

  float ax=0,ay=0,az=0,aw=0, bx=0,by=0,bz=0,bw=0, L=0;
  const size_t base = (size_t)b*2304 + (size_t)qt*16;
#pragma unroll 4
  for (int ks = 0; ks < 16; ++ks) {
    const size_t pb_ = base + ks;
    const float4* pp = pO4 + (pb_*8 + (size_t)f*4 + kcq)*64;
    const float4 t0 = pp[qlm];
    const float4 t1 = pp[qlm + 32];
    ax += t0.x; ay += t0.y; az += t0.z; aw += t0.w;
    bx += t1.x; by += t1.y; bz += t1.z; bw += t1.w;
    L  += pL[pb_*64 + l];
  }
  const float inv = 1.f / L;
  float* cp = ctxP + ((size_t)b*NPIX + (size_t)qt*64 + l)*32 + kcq*8;
  ((float4*)cp)[0] = make_float4(ax*inv, ay*inv, az*inv, aw*inv);
  ((float4*)cp)[1] = make_float4(bx*inv, by*inv, bz*inv, bw*inv);
}

// ---------------- fallback attention (LDS merge), pixel-major ctx ------------
__global__ __launch_bounds__(512, 6) void attn_mfma(
    const unsigned* __restrict__ qPA, const unsigned* __restrict__ qPB,
    const unsigned short* __restrict__ vBS,
    float* __restrict__ ctxP)
{
  __shared__ float slab[8][32][32];
  __shared__ float mlbuf[8][32];
  const int tid = threadIdx.x;
  const int w   = tid >> 6;
  const int l   = tid & 63;
  const int hi  = l >> 5;
  const int ql  = l & 31;
  const int blk = blockIdx.x;
  const int b   = blk / NTILE;
  const int tq  = blk % NTILE;
  const int q0  = tq * 32;

  const unsigned* qa_ = qPA + (size_t)b*QPA_B;
  const unsigned* qb_ = qPB + (size_t)b*QPA_B;
  const unsigned short* vb_ = vBS + (size_t)b*VBS_B;

  ABu bq1, bq2;
  bq1.v4 = *(const uint4v*)(qa_ + (size_t)tq*256 + hi*128 + ql*4);
  bq2.v4 = *(const uint4v*)(qb_ + (size_t)tq*256 + hi*128 + ql*4);

  f32x16 O;
#pragma unroll
  for (int r = 0; r < 16; ++r) O[r] = 0.f;
  float lsum = 0.f;

  for (int it = 0; it < 36; ++it) {
    const int t = it*8 + w;
    const size_t ko = (size_t)t*256 + hi*128 + ql*4;
    ABu ak1, ak2;
    ak1.v4 = *(const uint4v*)(qa_ + ko);
    ak2.v4 = *(const uint4v*)(qb_ + ko);
    const size_t vo = (size_t)t*1024 + (size_t)ql*16 + hi*8;
    const short8 av1 = *(const short8*)(vb_ + vo);
    const short8 av2 = *(const short8*)(vb_ + vo + 512);

    f32x16 s;
#pragma unroll
    for (int r = 0; r < 16; ++r) s[r] = 0.f;
    s = MFMA32(ak1.s, bq1.s, s);
    s = MFMA32(ak2.s, bq2.s, s);

    float p[16];
#pragma unroll
    for (int r = 0; r < 16; ++r) p[r] = __builtin_amdgcn_exp2f(s[r]);
    lsum += (((p[0]+p[1])+(p[2]+p[3])) + ((p[4]+p[5])+(p[6]+p[7])))
          + (((p[8]+p[9])+(p[10]+p[11])) + ((p[12]+p[13])+(p[14]+p[15])));

    unsigned a0 = pk2(p[0],p[1]),  a1 = pk2(p[2],p[3]);
    unsigned b0 = pk2(p[4],p[5]),  b1 = pk2(p[6],p[7]);
    unsigned a2 = pk2(p[8],p[9]),  a3 = pk2(p[10],p[11]);
    unsigned b2 = pk2(p[12],p[13]),b3 = pk2(p[14],p[15]);
    plswap(a0,b0); plswap(a1,b1); plswap(a2,b2); plswap(a3,b3);
    ABu pb1, pb2;
    pb1.u[0]=a0; pb1.u[1]=a1; pb1.u[2]=b0; pb1.u[3]=b1;
    pb2.u[0]=a2; pb2.u[1]=a3; pb2.u[2]=b2; pb2.u[3]=b3;

    O = MFMA32(av1, pb1.s, O);
    O = MFMA32(av2, pb2.s, O);
  }

  lsum += __shfl_xor(lsum, 32);
  if (hi == 0) mlbuf[w][ql] = lsum;
#pragma unroll
  for (int r = 0; r < 16; ++r)
    slab[w][(r&3) + 8*(r>>2) + 4*hi][ql] = O[r];
  __syncthreads();

  {
    const int q  = tid & 31;
    const int kh = tid >> 5;
    float L = 0.f;
#pragma unroll
    for (int ww = 0; ww < 8; ++ww) L += mlbuf[ww][q];
    const float inv = 1.f / L;
#pragma unroll
    for (int i = 0; i < 2; ++i) {
      const int kc = kh + 16*i;
      float acc = 0.f;
#pragma unroll
      for (int ww = 0; ww < 8; ++ww) acc += slab[ww][kc][q];
      ctxP[((size_t)b*NPIX + q0 + q)*32 + kc] = acc * inv;
    }
  }
}

// ---------------- g = relu(Wf*ctx + bf), pixel-major ------------------------
// 288 blocks x 256 thr; thread = (pixel, channel-quarter of 8).
__global__ __launch_bounds__(256) void g_kernel(
    const float* __restrict__ ctxP, const float* __restrict__ Wf,
    const float* __restrict__ bf, float* __restrict__ gP)
{
  __shared__ float4 swf[256];   // Wf 32x32
  const int tid = threadIdx.x;
  const int blk = blockIdx.x;        // 288 = 2*144
  const int b   = blk / 144;
  const int pg  = blk % 144;
  swf[tid] = ((const float4*)Wf)[tid];
  __syncthreads();
  const int nl = tid >> 2;           // 0..63
  const int cq = tid & 3;
  const int n  = pg*64 + nl;
  float cc[32];
  const float4* cp = (const float4*)(ctxP + ((size_t)b*NPIX + n)*32);
#pragma unroll
  for (int i = 0; i < 8; ++i) {
    const float4 t = cp[i];
    cc[4*i] = t.x; cc[4*i+1] = t.y; cc[4*i+2] = t.z; cc[4*i+3] = t.w;
  }
  float r[8];
#pragma unroll
  for (int jj = 0; jj < 8; ++jj) {
    const int j = cq*8 + jj;
    float acc = bf[j];
#pragma unroll
    for (int k8 = 0; k8 < 8; ++k8) {
      const float4 wv = swf[j*8 + k8];
      acc += wv.x*cc[4*k8] + wv.y*cc[4*k8+1] + wv.z*cc[4*k8+2] + wv.w*cc[4*k8+3];
    }
    r[jj] = fmaxf(acc, 0.f);
  }
  float4* go = (float4*)(gP + ((size_t)b*NPIX + n)*32 + cq*8);
  go[0] = make_float4(r[0], r[1], r[2], r[3]);
  go[1] = make_float4(r[4], r[5], r[6], r[7]);
}

// ---------------- epilogue: out = x + Wu*g + bu ------------------------------
// 1152 blocks x 256 thr (4608 waves). Thread = (pixel, 16-channel group).
__global__ __launch_bounds__(256) void epi_v3(
    const float* __restrict__ x, const float* __restrict__ gP,
    const float* __restrict__ Wu, const float* __restrict__ bu,
    float* __restrict__ out)
{
  __shared__ float4 swu[512];   // 64 Wu rows x 32 f32 = 8 KB
  const int tid = threadIdx.x;
  const int w   = tid >> 6;
  const int l   = tid & 63;
  const int blk = blockIdx.x;          // 1152 = 2 * 4 * 144
  const int b   = blk / 576;
  const int rem = blk % 576;
  const int cquad = rem / 144;         // 0..3
  const int pg  = rem % 144;
  const int co  = cquad*4 + w;         // 16-channel group 0..15
  const int n   = pg*64 + l;
#pragma unroll
  for (int it = 0; it < 2; ++it)
    swu[it*256 + tid] = ((const float4*)Wu)[cquad*512 + it*256 + tid];
  __syncthreads();
  float gg[32];
  const float4* gp = (const float4*)(gP + ((size_t)b*NPIX + n)*32);
#pragma unroll
  for (int i = 0; i < 8; ++i) {
    const float4 t = gp[i];
    gg[4*i] = t.x; gg[4*i+1] = t.y; gg[4*i+2] = t.z; gg[4*i+3] = t.w;
  }
  const float* xb = x + ((size_t)b*CCH + co*16)*NPIX + n;
  float* ob = out + ((size_t)b*CCH + co*16)*NPIX + n;
#pragma unroll
  for (int c = 0; c < 16; ++c) {
    float acc = bu[co*16 + c];
#pragma unroll
    for (int j = 0; j < 8; ++j) {
      const float4 wv = swu[(w*16 + c)*8 + j];
      acc += wv.x*gg[4*j] + wv.y*gg[4*j+1] + wv.z*gg[4*j+2] + wv.w*gg[4*j+3];
    }
    ob[(size_t)c*NPIX] = xb[(size_t)c*NPIX] + acc;
  }
}

extern "C" void kernel_launch(void* const* d_in, const int* in_sizes, int n_in,
                              void* d_out, int out_size, void* d_ws, size_t ws_size,
                              hipStream_t stream) {
  (void)in_sizes; (void)n_in; (void)out_size;
  const float* x     = (const float*)d_in[0];
  const float* human = (const float*)d_in[1];
  const float* Wq    = (const float*)d_in[2];
  const float* bq    = (const float*)d_in[3];
  const float* Wd    = (const float*)d_in[4];
  const float* bd    = (const float*)d_in[5];
  const float* Wf    = (const float*)d_in[6];
  const float* bf    = (const float*)d_in[7];
  const float* Wu    = (const float*)d_in[8];
  const float* bu    = (const float*)d_in[9];
  float* out = (float*)d_out;

  unsigned* qPA       = (unsigned*)d_ws;
  unsigned* qPB       = qPA + (size_t)NB*QPA_B;
  unsigned short* vBS = (unsigned short*)(qPB + (size_t)NB*QPA_B);
  float* ctxP         = (float*)(vBS + (size_t)NB*VBS_B);          // NB*NPIX*32 f32
  float* gP           = ctxP + (size_t)NB*NPIX*32;                 // NB*NPIX*32 f32
  float4* pO4         = (float4*)(gP + (size_t)NB*NPIX*32);        // 4608*8*64 float4
  float* pL           = (float*)(pO4 + (size_t)4608*8*64);         // 4608*64 f32

  const size_t need = ((char*)(pL + (size_t)4608*64)) - (char*)d_ws;

  proj_mfma<<<576, 512, 0, stream>>>(x, human, Wq, bq, Wd, bd, qPA, qPB, vBS);
  if (ws_size >= need) {
    attn_wave<<<1152, 256, 0, stream>>>(qPA, qPB, vBS, pO4, pL);
    attn_merge<<<1152, 64, 0, stream>>>(pO4, pL, ctxP);
  } else {
    attn_mfma<<<576, 512, 0, stream>>>(qPA, qPB, vBS, ctxP);
  }
  g_kernel<<<288, 256, 0, stream>>>(ctxP, Wf, bf, gP);
  epi_v3<<<1152, 256, 0, stream>>>(x, gP, Wu, bu, out);
}

// Round 12
// 166.383 us; speedup vs baseline: 1.3918x; 1.1862x over previous
//
#include <hip/hip_runtime.h>
#include <hip/hip_bf16.h>

#define NB 2
#define CCH 256
#define NPIX 9216      // 96*96
#define KCH 32
#define NTILE 288      // NPIX / 32
// sqrt( (1/sqrt(32)) * log2(e) ): folded into q at projection time, so
// S = (qP . kP) comes out directly in log2 units (softmax via exp2).
#define SQSCALE 0.5050098f

// workspace strides (per batch)
#define QPA_B 73728u     // 288 tiles * 2 hi * 32 lanes * 4 dwords
#define VBS_B 294912u    // 288 tiles * 2 half * 32 rows * 2 hi * 8 u16

typedef __attribute__((ext_vector_type(8)))  short short8;   // bf16x8 MFMA operand
typedef __attribute__((ext_vector_type(16))) float f32x16;   // 32x32 accumulator
typedef __attribute__((ext_vector_type(4)))  unsigned uint4v;

union ABu { unsigned u[4]; uint4v v4; short8 s; };

__device__ __forceinline__ unsigned pk2(float a, float b) {
  __hip_bfloat162 h = __float22bfloat162_rn(make_float2(a, b));
  unsigned r; __builtin_memcpy(&r, &h, 4); return r;
}
__device__ __forceinline__ unsigned short bf1(float a) {
  __hip_bfloat16 h = __float2bfloat16(a);
  unsigned short r; __builtin_memcpy(&r, &h, 2); return r;
}
__device__ __forceinline__ float bfx(unsigned short h) {   // bf16 -> f32 (exact)
  unsigned v = ((unsigned)h) << 16;
  float f; __builtin_memcpy(&f, &v, 4); return f;
}
// split a,b into bf16 hi pair and bf16 lo (residual) pair, packed dwords
__device__ __forceinline__ void split_pk(float a, float b, unsigned &hp, unsigned &lp) {
  unsigned short ha = bf1(a), hb_ = bf1(b);
  hp = (unsigned)ha | ((unsigned)hb_ << 16);
  unsigned short la = bf1(a - bfx(ha)), lb = bf1(b - bfx(hb_));
  lp = (unsigned)la | ((unsigned)lb << 16);
}
// exchange halves: after swap both lane-halves hold both operand words
__device__ __forceinline__ void plswap(unsigned &a, unsigned &b) {
  auto r = __builtin_amdgcn_permlane32_swap(a, b, false, false);
  a = r[0]; b = r[1];
}

#define MFMA32(a, b, c) __builtin_amdgcn_mfma_f32_32x32x16_bf16((a), (b), (c), 0, 0, 0)

// ---------------- MFMA projection: q = (Wq*human + bq)*scale, v = Wd*x + bd ----
// 576 blocks x 8 waves (8-way K-split over 256 channels, 32 each) for 4608
// waves of latency hiding. Split-bf16 (hi+lo, 3-term) keeps ~f32 precision.
__global__ __launch_bounds__(512, 4) void proj_mfma(
    const float* __restrict__ x, const float* __restrict__ human,
    const float* __restrict__ Wq, const float* __restrict__ bq,
    const float* __restrict__ Wd, const float* __restrict__ bd,
    unsigned* __restrict__ qPA,         // (B, 288, 2, 32, 4) kc-pairs 0..7
    unsigned* __restrict__ qPB,         // (B, 288, 2, 32, 4) kc-pairs 8..15
    unsigned short* __restrict__ vBS)   // (B, 288, 2, 32, 2, 8) bf16
{
  __shared__ float4 slab[8][8][64];   // 64 KB: [wave][frag-quad][lane]
  const int tid = threadIdx.x;
  const int w   = tid >> 6;           // K-eighth
  const int l   = tid & 63;
  const int hi  = l >> 5;
  const int ql  = l & 31;
  const int blk = blockIdx.x;         // 576
  const int b   = blk / NTILE;
  const int tN  = blk % NTILE;
  const int n0  = tN * 32;
  const int c0  = w * 32;
  const float* hb = human + (size_t)b*CCH*NPIX;
  const float* xb = x + (size_t)b*CCH*NPIX;

  ABu aqh[2], aqlo[2], adh[2], adlo[2];
#pragma unroll
  for (int s = 0; s < 2; ++s) {
    const int cbase = c0 + 16*s + 8*hi;
#pragma unroll
    for (int j = 0; j < 4; ++j) {
      const float q0 = Wq[ql*CCH + cbase + 2*j], q1 = Wq[ql*CCH + cbase + 2*j + 1];
      const float d0 = Wd[ql*CCH + cbase + 2*j], d1 = Wd[ql*CCH + cbase + 2*j + 1];
      split_pk(q0, q1, aqh[s].u[j], aqlo[s].u[j]);
      split_pk(d0, d1, adh[s].u[j], adlo[s].u[j]);
    }
  }

  f32x16 qa, va;
#pragma unroll
  for (int r = 0; r < 16; ++r) { qa[r] = 0.f; va[r] = 0.f; }

#pragma unroll
  for (int s = 0; s < 2; ++s) {
    const int cbase = c0 + 16*s + 8*hi;
    ABu bhh, bhl, bxh, bxl;
#pragma unroll
    for (int j = 0; j < 4; ++j) {
      const float h0 = hb[(size_t)(cbase + 2*j  )*NPIX + n0 + ql];
      const float h1 = hb[(size_t)(cbase + 2*j+1)*NPIX + n0 + ql];
      const float x0 = xb[(size_t)(cbase + 2*j  )*NPIX + n0 + ql];
      const float x1 = xb[(size_t)(cbase + 2*j+1)*NPIX + n0 + ql];
      split_pk(h0, h1, bhh.u[j], bhl.u[j]);
      split_pk(x0, x1, bxh.u[j], bxl.u[j]);
    }
    qa = MFMA32(aqh[s].s,  bhh.s, qa);
    qa = MFMA32(aqh[s].s,  bhl.s, qa);
    qa = MFMA32(aqlo[s].s, bhh.s, qa);
    va = MFMA32(adh[s].s,  bxh.s, va);
    va = MFMA32(adh[s].s,  bxl.s, va);
    va = MFMA32(adlo[s].s, bxh.s, va);
  }

#pragma unroll
  for (int jf = 0; jf < 4; ++jf) {
    slab[w][jf  ][l] = make_float4(qa[4*jf], qa[4*jf+1], qa[4*jf+2], qa[4*jf+3]);
    slab[w][4+jf][l] = make_float4(va[4*jf], va[4*jf+1], va[4*jf+2], va[4*jf+3]);
  }
  __syncthreads();
  if (w == 0) {
    unsigned* qpa = qPA + (size_t)b*QPA_B;
    unsigned* qpb = qPB + (size_t)b*QPA_B;
    unsigned short* vbs = vBS + (size_t)b*VBS_B;
#pragma unroll
    for (int jf = 0; jf < 4; ++jf) {
      const int kc = 8*jf + 4*hi;
      float sx=0, sy=0, sz=0, sw=0, tx=0, ty=0, tz=0, tw=0;
#pragma unroll
      for (int ww = 0; ww < 8; ++ww) {
        const float4 sq = slab[ww][jf][l];
        const float4 tv = slab[ww][4+jf][l];
        sx += sq.x; sy += sq.y; sz += sq.z; sw += sq.w;
        tx += tv.x; ty += tv.y; tz += tv.z; tw += tv.w;
      }
      const float v0 = (sx + bq[kc+0]) * SQSCALE;
      const float v1 = (sy + bq[kc+1]) * SQSCALE;
      const float v2 = (sz + bq[kc+2]) * SQSCALE;
      const float v3 = (sw + bq[kc+3]) * SQSCALE;
      const int p0 = 4*jf + 2*hi;
      unsigned* a0p = (p0 < 8) ? qpa : qpb;
      a0p[(size_t)tN*256 + ((p0&7)>>2)*128 + ql*4 + (p0&3)] = pk2(v0, v1);
      const int p1 = p0 + 1;
      unsigned* a1p = (p1 < 8) ? qpa : qpb;
      a1p[(size_t)tN*256 + ((p1&7)>>2)*128 + ql*4 + (p1&3)] = pk2(v2, v3);
      const size_t vbase = (size_t)tN*1024 + (size_t)(ql>>4)*512 + (size_t)(ql&15);
      vbs[vbase + (size_t)(kc+0)*16] = bf1(tx + bd[kc+0]);
      vbs[vbase + (size_t)(kc+1)*16] = bf1(ty + bd[kc+1]);
      vbs[vbase + (size_t)(kc+2)*16] = bf1(tz + bd[kc+2]);
      vbs[vbase + (size_t)(kc+3)*16] = bf1(tw + bd[kc+3]);
    }
  }
}

// ---------------- attention main: one wave per (64-query tile, key-16th) ------
// Round-9 config (4608 x 64, bounds (64,4) -- proven 51 us; rounds 10/11's
// repackaging regressed) + 1-deep register prefetch of next K/V tile so L2
// latency hides under the MFMA/softmax chain.
__global__ __launch_bounds__(64, 4) void attn_wave(
    const unsigned* __restrict__ qPA, const unsigned* __restrict__ qPB,
    const unsigned short* __restrict__ vBS,
    float4* __restrict__ pO4,           // [4608][2][4][64] float4
    float* __restrict__ pL)             // [4608][64]
{
  const int l   = threadIdx.x;
  const int hi  = l >> 5;
  const int ql  = l & 31;
  const int blk = blockIdx.x;               // 4608
  const int swz = (blk & 7)*576 + (blk >> 3);   // XCD-contiguous chunks
  const int b   = swz / 2304;
  const int r2  = swz % 2304;
  const int qt  = r2 >> 4;                  // 0..143 (64-query tile)
  const int ks  = r2 & 15;                  // key-16th

  const unsigned* qa_ = qPA + (size_t)b*QPA_B;
  const unsigned* qb_ = qPB + (size_t)b*QPA_B;
  const unsigned short* vb_ = vBS + (size_t)b*VBS_B;

  ABu bqA1, bqA2, bqB1, bqB2;
  bqA1.v4 = *(const uint4v*)(qa_ + (size_t)(2*qt  )*256 + hi*128 + ql*4);
  bqA2.v4 = *(const uint4v*)(qb_ + (size_t)(2*qt  )*256 + hi*128 + ql*4);
  bqB1.v4 = *(const uint4v*)(qa_ + (size_t)(2*qt+1)*256 + hi*128 + ql*4);
  bqB2.v4 = *(const uint4v*)(qb_ + (size_t)(2*qt+1)*256 + hi*128 + ql*4);

  f32x16 OA, OB, Z;
#pragma unroll
  for (int r = 0; r < 16; ++r) { OA[r] = 0.f; OB[r] = 0.f; Z[r] = 0.f; }
  float lsA = 0.f, lsB = 0.f;

  const int t0 = ks*18;
  // preload tile t0
  ABu ak1, ak2;
  short8 av1, av2;
  {
    const size_t ko = (size_t)t0*256 + hi*128 + ql*4;
    ak1.v4 = *(const uint4v*)(qa_ + ko);
    ak2.v4 = *(const uint4v*)(qb_ + ko);
    const size_t vo = (size_t)t0*1024 + (size_t)ql*16 + hi*8;
    av1 = *(const short8*)(vb_ + vo);
    av2 = *(const short8*)(vb_ + vo + 512);
  }

  for (int it = 0; it < 18; ++it) {
    // prefetch tile t+1 (clamped on last iter -> same loads, same work per call)
    const int tn = t0 + ((it < 17) ? it + 1 : it);
    ABu nk1, nk2;
    short8 nv1, nv2;
    {
      const size_t ko = (size_t)tn*256 + hi*128 + ql*4;
      nk1.v4 = *(const uint4v*)(qa_ + ko);
      nk2.v4 = *(const uint4v*)(qb_ + ko);
      const size_t vo = (size_t)tn*1024 + (size_t)ql*16 + hi*8;
      nv1 = *(const short8*)(vb_ + vo);
      nv2 = *(const short8*)(vb_ + vo + 512);
    }

    // ---- frag A ----
    f32x16 s = MFMA32(ak1.s, bqA1.s, Z);
    s = MFMA32(ak2.s, bqA2.s, s);
    float p[16];
#pragma unroll
    for (int r = 0; r < 16; ++r) p[r] = __builtin_amdgcn_exp2f(s[r]);
    lsA += (((p[0]+p[1])+(p[2]+p[3])) + ((p[4]+p[5])+(p[6]+p[7])))
         + (((p[8]+p[9])+(p[10]+p[11])) + ((p[12]+p[13])+(p[14]+p[15])));
    {
      unsigned a0 = pk2(p[0],p[1]),  a1 = pk2(p[2],p[3]);
      unsigned b0 = pk2(p[4],p[5]),  b1 = pk2(p[6],p[7]);
      unsigned a2 = pk2(p[8],p[9]),  a3 = pk2(p[10],p[11]);
      unsigned b2 = pk2(p[12],p[13]),b3 = pk2(p[14],p[15]);
      plswap(a0,b0); plswap(a1,b1); plswap(a2,b2); plswap(a3,b3);
      ABu pb1, pb2;
      pb1.u[0]=a0; pb1.u[1]=a1; pb1.u[2]=b0; pb1.u[3]=b1;
      pb2.u[0]=a2; pb2.u[1]=a3; pb2.u[2]=b2; pb2.u[3]=b3;
      OA = MFMA32(av1, pb1.s, OA);
      OA = MFMA32(av2, pb2.s, OA);
    }
    // ---- frag B ----
    s = MFMA32(ak1.s, bqB1.s, Z);
    s = MFMA32(ak2.s, bqB2.s, s);
#pragma unroll
    for (int r = 0; r < 16; ++r) p[r] = __builtin_amdgcn_exp2f(s[r]);
    lsB += (((p[0]+p[1])+(p[2]+p[3])) + ((p[4]+p[5])+(p[6]+p[7])))
         + (((p[8]+p[9])+(p[10]+p[11])) + ((p[12]+p[13])+(p[14]+p[15])));
    {
      unsigned a0 = pk2(p[0],p[1]),  a1 = pk2(p[2],p[3]);
      unsigned b0 = pk2(p[4],p[5]),  b1 = pk2(p[6],p[7]);
      unsigned a2 = pk2(p[8],p[9]),  a3 = pk2(p[10],p[11]);
      unsigned b2 = pk2(p[12],p[13]),b3 = pk2(p[14],p[15]);
      plswap(a0,b0); plswap(a1,b1); plswap(a2,b2); plswap(a3,b3);
      ABu pb1, pb2;
      pb1.u[0]=a0; pb1.u[1]=a1; pb1.u[2]=b0; pb1.u[3]=b1;
      pb2.u[0]=a2; pb2.u[1]=a3; pb2.u[2]=b2; pb2.u[3]=b3;
      OB = MFMA32(av1, pb1.s, OB);
      OB = MFMA32(av2, pb2.s, OB);
    }

    ak1 = nk1; ak2 = nk2; av1 = nv1; av2 = nv2;
  }

  lsA += __shfl_xor(lsA, 32);
  lsB += __shfl_xor(lsB, 32);
#pragma unroll
  for (int rq = 0; rq < 4; ++rq) {
    pO4[((size_t)swz*8 + rq    )*64 + l] = make_float4(OA[4*rq], OA[4*rq+1], OA[4*rq+2], OA[4*rq+3]);
    pO4[((size_t)swz*8 + 4 + rq)*64 + l] = make_float4(OB[4*rq], OB[4*rq+1], OB[4*rq+2], OB[4*rq+3]);
  }
  if (l < 32) {
    pL[(size_t)swz*64 + l]      = lsA;
    pL[(size_t)swz*64 + 32 + l] = lsB;
  }
}

// ---------------- attention merge: sum 16 key-splits, normalize --------------
// writes ctx PIXEL-MAJOR: ctxP[b][n][kc], 32 f32 per pixel
__global__ __launch_bounds__(64) void attn_merge(
    const float4* __restrict__ pO4, const float* __restrict__ pL,
    float* __restrict__ ctxP)
{
  const int l   = threadIdx.x;           // q64
  const int blk = blockIdx.x;            // 1152 = 2 * 144 * 4
  const int b   = blk / 576;
  const int rem = blk % 576;
  const int qt  = rem >> 2;
  const int kcq = rem & 3;
  const int f   = l >> 5;
  const int qlm = l & 31;

  float ax=0,ay=0,az=0,aw=0, bx=0,by=0,bz=0,bw=0, L=0;
  const size_t base = (size_t)b*2304 + (size_t)qt*16;
#pragma unroll 4
  for (int ks = 0; ks < 16; ++ks) {
    const size_t pb_ = base + ks;
    const float4* pp = pO4 + (pb_*8 + (size_t)f*4 + kcq)*64;
    const float4 t0 = pp[qlm];
    const float4 t1 = pp[qlm + 32];
    ax += t0.x; ay += t0.y; az += t0.z; aw += t0.w;
    bx += t1.x; by += t1.y; bz += t1.z; bw += t1.w;
    L  += pL[pb_*64 + l];
  }
  const float inv = 1.f / L;
  float* cp = ctxP + ((size_t)b*NPIX + (size_t)qt*64 + l)*32 + kcq*8;
  ((float4*)cp)[0] = make_float4(ax*inv, ay*inv, az*inv, aw*inv);
  ((float4*)cp)[1] = make_float4(bx*inv, by*inv, bz*inv, bw*inv);
}

// ---------------- fallback attention (LDS merge), pixel-major ctx ------------
__global__ __launch_bounds__(512, 6) void attn_mfma(
    const unsigned* __restrict__ qPA, const unsigned* __restrict__ qPB,
    const unsigned short* __restrict__ vBS,
    float* __restrict__ ctxP)
{
  __shared__ float slab[8][32][32];
  __shared__ float mlbuf[8][32];
  const int tid = threadIdx.x;
  const int w   = tid >> 6;
  const int l   = tid & 63;
  const int hi  = l >> 5;
  const int ql  = l & 31;
  const int blk = blockIdx.x;
  const int b   = blk / NTILE;
  const int tq  = blk % NTILE;
  const int q0  = tq * 32;

  const unsigned* qa_ = qPA + (size_t)b*QPA_B;
  const unsigned* qb_ = qPB + (size_t)b*QPA_B;
  const unsigned short* vb_ = vBS + (size_t)b*VBS_B;

  ABu bq1, bq2;
  bq1.v4 = *(const uint4v*)(qa_ + (size_t)tq*256 + hi*128 + ql*4);
  bq2.v4 = *(const uint4v*)(qb_ + (size_t)tq*256 + hi*128 + ql*4);

  f32x16 O;
#pragma unroll
  for (int r = 0; r < 16; ++r) O[r] = 0.f;
  float lsum = 0.f;

  for (int it = 0; it < 36; ++it) {
    const int t = it*8 + w;
    const size_t ko = (size_t)t*256 + hi*128 + ql*4;
    ABu ak1, ak2;
    ak1.v4 = *(const uint4v*)(qa_ + ko);
    ak2.v4 = *(const uint4v*)(qb_ + ko);
    const size_t vo = (size_t)t*1024 + (size_t)ql*16 + hi*8;
    const short8 av1 = *(const short8*)(vb_ + vo);
    const short8 av2 = *(const short8*)(vb_ + vo + 512);

    f32x16 s;
#pragma unroll
    for (int r = 0; r < 16; ++r) s[r] = 0.f;
    s = MFMA32(ak1.s, bq1.s, s);
    s = MFMA32(ak2.s, bq2.s, s);

    float p[16];
#pragma unroll
    for (int r = 0; r < 16; ++r) p[r] = __builtin_amdgcn_exp2f(s[r]);
    lsum += (((p[0]+p[1])+(p[2]+p[3])) + ((p[4]+p[5])+(p[6]+p[7])))
          + (((p[8]+p[9])+(p[10]+p[11])) + ((p[12]+p[13])+(p[14]+p[15])));

    unsigned a0 = pk2(p[0],p[1]),  a1 = pk2(p[2],p[3]);
    unsigned b0 = pk2(p[4],p[5]),  b1 = pk2(p[6],p[7]);
    unsigned a2 = pk2(p[8],p[9]),  a3 = pk2(p[10],p[11]);
    unsigned b2 = pk2(p[12],p[13]),b3 = pk2(p[14],p[15]);
    plswap(a0,b0); plswap(a1,b1); plswap(a2,b2); plswap(a3,b3);
    ABu pb1, pb2;
    pb1.u[0]=a0; pb1.u[1]=a1; pb1.u[2]=b0; pb1.u[3]=b1;
    pb2.u[0]=a2; pb2.u[1]=a3; pb2.u[2]=b2; pb2.u[3]=b3;

    O = MFMA32(av1, pb1.s, O);
    O = MFMA32(av2, pb2.s, O);
  }

  lsum += __shfl_xor(lsum, 32);
  if (hi == 0) mlbuf[w][ql] = lsum;
#pragma unroll
  for (int r = 0; r < 16; ++r)
    slab[w][(r&3) + 8*(r>>2) + 4*hi][ql] = O[r];
  __syncthreads();

  {
    const int q  = tid & 31;
    const int kh = tid >> 5;
    float L = 0.f;
#pragma unroll
    for (int ww = 0; ww < 8; ++ww) L += mlbuf[ww][q];
    const float inv = 1.f / L;
#pragma unroll
    for (int i = 0; i < 2; ++i) {
      const int kc = kh + 16*i;
      float acc = 0.f;
#pragma unroll
      for (int ww = 0; ww < 8; ++ww) acc += slab[ww][kc][q];
      ctxP[((size_t)b*NPIX + q0 + q)*32 + kc] = acc * inv;
    }
  }
}

// ---------------- g = relu(Wf*ctx + bf), pixel-major ------------------------
// 288 blocks x 256 thr; thread = (pixel, channel-quarter of 8).
__global__ __launch_bounds__(256) void g_kernel(
    const float* __restrict__ ctxP, const float* __restrict__ Wf,
    const float* __restrict__ bf, float* __restrict__ gP)
{
  __shared__ float4 swf[256];   // Wf 32x32
  const int tid = threadIdx.x;
  const int blk = blockIdx.x;        // 288 = 2*144
  const int b   = blk / 144;
  const int pg  = blk % 144;
  swf[tid] = ((const float4*)Wf)[tid];
  __syncthreads();
  const int nl = tid >> 2;           // 0..63
  const int cq = tid & 3;
  const int n  = pg*64 + nl;
  float cc[32];
  const float4* cp = (const float4*)(ctxP + ((size_t)b*NPIX + n)*32);
#pragma unroll
  for (int i = 0; i < 8; ++i) {
    const float4 t = cp[i];
    cc[4*i] = t.x; cc[4*i+1] = t.y; cc[4*i+2] = t.z; cc[4*i+3] = t.w;
  }
  float r[8];
#pragma unroll
  for (int jj = 0; jj < 8; ++jj) {
    const int j = cq*8 + jj;
    float acc = bf[j];
#pragma unroll
    for (int k8 = 0; k8 < 8; ++k8) {
      const float4 wv = swf[j*8 + k8];
      acc += wv.x*cc[4*k8] + wv.y*cc[4*k8+1] + wv.z*cc[4*k8+2] + wv.w*cc[4*k8+3];
    }
    r[jj] = fmaxf(acc, 0.f);
  }
  float4* go = (float4*)(gP + ((size_t)b*NPIX + n)*32 + cq*8);
  go[0] = make_float4(r[0], r[1], r[2], r[3]);
  go[1] = make_float4(r[4], r[5], r[6], r[7]);
}

// ---------------- epilogue: out = x + Wu*g + bu ------------------------------
// 1152 blocks x 256 thr (4608 waves). Thread = (pixel, 16-channel group).
__global__ __launch_bounds__(256) void epi_v3(
    const float* __restrict__ x, const float* __restrict__ gP,
    const float* __restrict__ Wu, const float* __restrict__ bu,
    float* __restrict__ out)
{
  __shared__ float4 swu[512];   // 64 Wu rows x 32 f32 = 8 KB
  const int tid = threadIdx.x;
  const int w   = tid >> 6;
  const int l   = tid & 63;
  const int blk = blockIdx.x;          // 1152 = 2 * 4 * 144
  const int b   = blk / 576;
  const int rem = blk % 576;
  const int cquad = rem / 144;         // 0..3
  const int pg  = rem % 144;
  const int co  = cquad*4 + w;         // 16-channel group 0..15
  const int n   = pg*64 + l;
#pragma unroll
  for (int it = 0; it < 2; ++it)
    swu[it*256 + tid] = ((const float4*)Wu)[cquad*512 + it*256 + tid];
  __syncthreads();
  float gg[32];
  const float4* gp = (const float4*)(gP + ((size_t)b*NPIX + n)*32);
#pragma unroll
  for (int i = 0; i < 8; ++i) {
    const float4 t = gp[i];
    gg[4*i] = t.x; gg[4*i+1] = t.y; gg[4*i+2] = t.z; gg[4*i+3] = t.w;
  }
  const float* xb = x + ((size_t)b*CCH + co*16)*NPIX + n;
  float* ob = out + ((size_t)b*CCH + co*16)*NPIX + n;
#pragma unroll
  for (int c = 0; c < 16; ++c) {
    float acc = bu[co*16 + c];
#pragma unroll
    for (int j = 0; j < 8; ++j) {
      const float4 wv = swu[(w*16 + c)*8 + j];
      acc += wv.x*gg[4*j] + wv.y*gg[4*j+1] + wv.z*gg[4*j+2] + wv.w*gg[4*j+3];
    }
    ob[(size_t)c*NPIX] = xb[(size_t)c*NPIX] + acc;
  }
}

extern "C" void kernel_launch(void* const* d_in, const int* in_sizes, int n_in,
                              void* d_out, int out_size, void* d_ws, size_t ws_size,
                              hipStream_t stream) {
  (void)in_sizes; (void)n_in; (void)out_size;
  const float* x     = (const float*)d_in[0];
  const float* human = (const float*)d_in[1];
  const float* Wq    = (const float*)d_in[2];
  const float* bq    = (const float*)d_in[3];
  const float* Wd    = (const float*)d_in[4];
  const float* bd    = (const float*)d_in[5];
  const float* Wf    = (const float*)d_in[6];
  const float* bf    = (const float*)d_in[7];
  const float* Wu    = (const float*)d_in[8];
  const float* bu    = (const float*)d_in[9];
  float* out = (float*)d_out;

  unsigned* qPA       = (unsigned*)d_ws;
  unsigned* qPB       = qPA + (size_t)NB*QPA_B;
  unsigned short* vBS = (unsigned short*)(qPB + (size_t)NB*QPA_B);
  float* ctxP         = (float*)(vBS + (size_t)NB*VBS_B);          // NB*NPIX*32 f32
  float* gP           = ctxP + (size_t)NB*NPIX*32;                 // NB*NPIX*32 f32
  float4* pO4         = (float4*)(gP + (size_t)NB*NPIX*32);        // 4608*8*64 float4
  float* pL           = (float*)(pO4 + (size_t)4608*8*64);         // 4608*64 f32

  const size_t need = ((char*)(pL + (size_t)4608*64)) - (char*)d_ws;

  proj_mfma<<<576, 512, 0, stream>>>(x, human, Wq, bq, Wd, bd, qPA, qPB, vBS);
  if (ws_size >= need) {
    attn_wave<<<4608, 64, 0, stream>>>(qPA, qPB, vBS, pO4, pL);
    attn_merge<<<1152, 64, 0, stream>>>(pO4, pL, ctxP);
  } else {
    attn_mfma<<<576, 512, 0, stream>>>(qPA, qPB, vBS, ctxP);
  }
  g_kernel<<<288, 256, 0, stream>>>(ctxP, Wf, bf, gP);
  epi_v3<<<1152, 256, 0, stream>>>(x, gP, Wu, bu, out);
}